// Round 5
// baseline (202.944 us; speedup 1.0000x reference)
//
#include <hip/hip_runtime.h>
#include <math.h>

// Problem shape (fixed): out (32,128,128,9,5) f32, target (32,128,128,3,6) f32
constexpr int kGX     = 128;
constexpr int kGY     = 128;
constexpr int kA      = 9;
constexpr int kNCells = 32 * kGX * kGY;              // 524288
constexpr int kN      = kNCells * kA;                // 4718592

constexpr int kCellsPerTile = 32;
constexpr int kTiles  = kNCells / kCellsPerTile;     // 16384
constexpr int kT      = 4;                           // tiles per wave (pipelined)
constexpr int kBlocks = kTiles / (4 * kT);           // 1024
static_assert(kBlocks * 4 * kT == kTiles, "exact cover");

constexpr int kOutF4  = kCellsPerTile * 45 / 4;      // 360 float4
constexpr int kTgtF4  = kCellsPerTile * 18 / 4;      // 144 float4
constexpr int kTileF4 = kOutF4 + kTgtF4;             // 504 (8064 B / wave)

__device__ inline float frcp(float x) { return __builtin_amdgcn_rcpf(x); }

// Branchless full-range atan, A&S 4.4.49 poly on [0,1] (|eps| <= 1e-5).
__device__ inline float fast_atan(float r) {
    const float x = fabsf(r);
    const bool inv = x > 1.f;
    const float t = inv ? frcp(x) : x;
    const float t2 = t * t;
    float p = fmaf(t2, 0.0208351f, -0.0851330f);
    p = fmaf(t2, p, 0.1801410f);
    p = fmaf(t2, p, -0.3302995f);
    p = fmaf(t2, p, 0.9998660f);
    p = t * p;
    float res = inv ? (1.5707963f - p) : p;
    return r < 0.f ? -res : res;
}

// acc: mode==1 -> per-block partials acc[b*5+i]; mode==0 -> 5 global doubles (atomics)
__global__ __launch_bounds__(256)
void loss_main(const float* __restrict__ outp, const float* __restrict__ tgt,
               double* __restrict__ acc, int mode) {
    __shared__ float4 s_tile[4 * kTileF4];   // 32256 B, wave-private regions
    __shared__ double smem[4][5];

    const int lane = threadIdx.x & 63;
    const int wv   = threadIdx.x >> 6;
    float4* sw = s_tile + wv * kTileF4;
    const float* swf = (const float*)sw;
    const int tile0 = (blockIdx.x * 4 + wv) * kT;    // 4 consecutive tiles per wave

    // register staging buffer: 9 float4 / lane (the pipeline's "second buffer")
    float4 orr[6], trr[3];

    // ---- prologue: load tile0 into registers (coalesced dwordx4) ----
    {
        const float4* g = (const float4*)outp + (size_t)tile0 * kOutF4;
        #pragma unroll
        for (int j = 0; j < 5; ++j) orr[j] = g[j * 64 + lane];
        if (lane < 40) orr[5] = g[320 + lane];
        const float4* h = (const float4*)tgt + (size_t)tile0 * kTgtF4;
        trr[0] = h[lane]; trr[1] = h[64 + lane];
        if (lane < 16) trr[2] = h[128 + lane];
    }

    const int c  = lane >> 1;                        // cell within tile (2 lanes/cell)
    const int sa = lane & 1;                         // anchor parity
    float t_jsq = 0.f, t_all = 0.f, t_jbb = 0.f, t_huh = 0.f, t_zsd = 0.f;

    for (int t = 0; t < kT; ++t) {
        // ---- ds_write current tile (compiler waits vmcnt for THESE regs only) ----
        #pragma unroll
        for (int j = 0; j < 5; ++j) sw[j * 64 + lane] = orr[j];
        if (lane < 40) sw[320 + lane] = orr[5];
        sw[360 + lane] = trr[0]; sw[424 + lane] = trr[1];
        if (lane < 16) sw[488 + lane] = trr[2];
        // lgkmcnt(0) ONLY (vmcnt=63, expcnt=7 left unwaited): LDS writes visible,
        // register buffer free — next tile's global loads stay in flight.
        __builtin_amdgcn_s_waitcnt(0xC07F);

        // ---- prefetch tile t+1 into registers (in flight during compute) ----
        if (t + 1 < kT) {
            const int tn = tile0 + t + 1;
            const float4* g = (const float4*)outp + (size_t)tn * kOutF4;
            #pragma unroll
            for (int j = 0; j < 5; ++j) orr[j] = g[j * 64 + lane];
            if (lane < 40) orr[5] = g[320 + lane];
            const float4* h = (const float4*)tgt + (size_t)tn * kTgtF4;
            trr[0] = h[lane]; trr[1] = h[64 + lane];
            if (lane < 16) trr[2] = h[128 + lane];
        }

        // ---- compute tile t from LDS ----
        const int tile = tile0 + t;
        const int cell = tile * kCellsPerTile + c;
        const int gy = cell & (kGY - 1);
        const int gx = (cell >> 7) & (kGX - 1);

        const float* st = swf + 4 * kOutF4 + c * 18;
        const float acx = st[0], acy = st[1], aw = st[2], ah = st[3], conf = st[5];
        const bool pos = conf > 0.8f;

        const float zx = (float)gx * (1.f / kGX) + 0.5f / kGX;
        const float zy = (float)gy * (1.f / kGY) + 0.5f / kGY;
        const float ax1 = acx - 0.5f * aw, ax2 = acx + 0.5f * aw;
        const float ay1 = acy - 0.5f * ah, ay2 = acy + 0.5f * ah;
        const float area_a = aw * ah;
        const float atan_a = fast_atan(aw * frcp(ah));

        const float* ob = swf + c * 45 + sa * 5;

        t_jsq += pos ? (sa ? 4.f : 5.f) : 0.f;

        #pragma unroll
        for (int k = 0; k < 5; ++k) {
            const int a = sa + 2 * k;                // 0..8 (a==9 on sa=1,k=4: masked)
            const bool act = (a < kA);
            const float o0 = ob[k * 10 + 0], o1 = ob[k * 10 + 1], o2 = ob[k * 10 + 2];
            const float o3 = ob[k * 10 + 3], obj = ob[k * 10 + 4];

            const float bcx = o0 - 0.5f + zx;
            const float bcy = o1 - 0.5f + zy;
            const float bw  = o2 - 0.5f + (1.f / kGX);
            const float bh  = o3 - 0.5f + (1.f / kGY);
            const float bx1 = bcx - 0.5f * bw, bx2 = bcx + 0.5f * bw;
            const float by1 = bcy - 0.5f * bh, by2 = bcy + 0.5f * bh;

            const float iw = fminf(ax2, bx2) - fmaxf(ax1, bx1);
            const float ih = fminf(ay2, by2) - fmaxf(ay1, by1);
            const float cross = (iw > 0.f && ih > 0.f) ? iw * ih : 0.f;
            const float uni = area_a + bw * bh - cross;
            const float iou = cross * frcp(uni + 1e-6f);

            const float dx = bcx - acx, dy = bcy - acy;
            const float d2 = dx * dx + dy * dy;
            const float cw  = fmaxf(ax2, bx2) - fminf(ax1, bx1);
            const float chh = fmaxf(ay2, by2) - fminf(ay1, by1);
            const float c2 = cw * cw + chh * chh;
            const float diou = iou - d2 * frcp(c2);

            const float dat = atan_a - fast_atan(bw * frcp(bh));
            const float v = 0.4052847345693511f * dat * dat;   // 4/pi^2
            const float alpha = v * frcp(1.f - iou + v);
            const float los = 1.f - (diou - alpha * v);
            const float om = 1.f - obj;

            const bool p = pos && act;
            t_all += p ? (los + om) : 0.f;
            t_jbb += p ? iou : 0.f;
            t_huh += p ? om : 0.f;
            t_zsd += p ? om * om : (act ? obj * obj : 0.f);
        }
    }

    // ---- wave-64 butterfly reduce (double), cross-wave via LDS, block partial ----
    double vals[5] = {(double)t_jsq, (double)t_all, (double)t_jbb,
                      (double)t_huh, (double)t_zsd};
    #pragma unroll
    for (int i = 0; i < 5; ++i) {
        double x = vals[i];
        #pragma unroll
        for (int off = 32; off > 0; off >>= 1) x += __shfl_down(x, off, 64);
        vals[i] = x;
    }
    if (lane == 0) {
        #pragma unroll
        for (int i = 0; i < 5; ++i) smem[wv][i] = vals[i];
    }
    __syncthreads();
    if (threadIdx.x < 5) {
        const double sv = smem[0][threadIdx.x] + smem[1][threadIdx.x] +
                          smem[2][threadIdx.x] + smem[3][threadIdx.x];
        if (mode) acc[(size_t)blockIdx.x * 5 + threadIdx.x] = sv;
        else atomicAdd(&acc[threadIdx.x], sv);
    }
}

__global__ __launch_bounds__(256)
void loss_final(const double* __restrict__ acc, float* __restrict__ res, int n_part) {
    if (n_part > 0) {
        double v[5] = {0, 0, 0, 0, 0};
        for (int j = threadIdx.x; j < n_part; j += 256) {
            #pragma unroll
            for (int i = 0; i < 5; ++i) v[i] += acc[(size_t)j * 5 + i];
        }
        #pragma unroll
        for (int i = 0; i < 5; ++i) {
            double x = v[i];
            #pragma unroll
            for (int off = 32; off > 0; off >>= 1) x += __shfl_down(x, off, 64);
            v[i] = x;
        }
        __shared__ double sm[4][5];
        const int lane = threadIdx.x & 63, wv = threadIdx.x >> 6;
        if (lane == 0) {
            #pragma unroll
            for (int i = 0; i < 5; ++i) sm[wv][i] = v[i];
        }
        __syncthreads();
        if (threadIdx.x == 0) {
            #pragma unroll
            for (int i = 0; i < 5; ++i) v[i] = sm[0][i] + sm[1][i] + sm[2][i] + sm[3][i];
            const double jsq = v[0], total = (double)kN;
            res[0] = (float)(v[1] / jsq + v[4] / total);
            res[1] = (float)(v[2] / jsq);
            res[2] = (float)(v[3] / jsq);
        }
    } else if (threadIdx.x == 0) {
        const double jsq = acc[0], total = (double)kN;
        res[0] = (float)(acc[1] / jsq + acc[4] / total);
        res[1] = (float)(acc[2] / jsq);
        res[2] = (float)(acc[3] / jsq);
    }
}

extern "C" void kernel_launch(void* const* d_in, const int* in_sizes, int n_in,
                              void* d_out, int out_size, void* d_ws, size_t ws_size,
                              hipStream_t stream) {
    const float* outp = (const float*)d_in[0];
    const float* tgt  = (const float*)d_in[1];
    float* res = (float*)d_out;
    double* acc = (double*)d_ws;

    const bool partials = ws_size >= (size_t)kBlocks * 5 * sizeof(double);  // 40 KB
    if (!partials) hipMemsetAsync(acc, 0, 5 * sizeof(double), stream);
    loss_main<<<kBlocks, 256, 0, stream>>>(outp, tgt, acc, partials ? 1 : 0);
    loss_final<<<1, 256, 0, stream>>>(acc, res, partials ? kBlocks : 0);
}

// Round 6
// 175.874 us; speedup vs baseline: 1.1539x; 1.1539x over previous
//
#include <hip/hip_runtime.h>
#include <math.h>

// Problem shape (fixed): out (32,128,128,9,5) f32, target (32,128,128,3,6) f32
constexpr int kGX     = 128;
constexpr int kGY     = 128;
constexpr int kA      = 9;
constexpr int kNCells = 32 * kGX * kGY;              // 524288
constexpr int kN      = kNCells * kA;                // 4718592

constexpr int kCellsPerTile = 16;                    // small tile -> high residency
constexpr int kTiles  = kNCells / kCellsPerTile;     // 32768
constexpr int kBlocks = kTiles / 4;                  // 8192 (1 tile per wave)
static_assert(kBlocks * 4 == kTiles, "exact cover");

constexpr int kOutF4  = kCellsPerTile * 45 / 4;      // 180 float4
constexpr int kTgtF4  = kCellsPerTile * 18 / 4;      // 72 float4
constexpr int kTileF4 = kOutF4 + kTgtF4;             // 252 (4032 B / wave)

__device__ inline void gload_lds16(const void* gptr, void* lptr) {
    __builtin_amdgcn_global_load_lds(
        (const __attribute__((address_space(1))) unsigned int*)gptr,
        (__attribute__((address_space(3))) unsigned int*)lptr, 16, 0, 0);
}

__device__ inline float frcp(float x) { return __builtin_amdgcn_rcpf(x); }

// Branchless full-range atan, A&S 4.4.49 poly on [0,1] (|eps| <= 1e-5).
__device__ inline float fast_atan(float r) {
    const float x = fabsf(r);
    const bool inv = x > 1.f;
    const float t = inv ? frcp(x) : x;
    const float t2 = t * t;
    float p = fmaf(t2, 0.0208351f, -0.0851330f);
    p = fmaf(t2, p, 0.1801410f);
    p = fmaf(t2, p, -0.3302995f);
    p = fmaf(t2, p, 0.9998660f);
    p = t * p;
    float res = inv ? (1.5707963f - p) : p;
    return r < 0.f ? -res : res;
}

// acc: mode==1 -> per-block partials acc[b*5+i]; mode==0 -> 5 global doubles (atomics)
__global__ __launch_bounds__(256, 8)
void loss_main(const float* __restrict__ outp, const float* __restrict__ tgt,
               double* __restrict__ acc, int mode) {
    __shared__ float4 s_tile[4 * kTileF4];   // 16128 B, wave-private regions
    __shared__ float smem[4][5];

    const int lane = threadIdx.x & 63;
    const int wv   = threadIdx.x >> 6;
    float4* sw = s_tile + wv * kTileF4;
    const float* swf = (const float*)sw;
    const int tile = blockIdx.x * 4 + wv;    // 1 tile per wave

    // ---- wave-private staging: coalesced dwordx4 direct-to-LDS (no VGPR cost) ----
    {
        const float4* g = (const float4*)outp + (size_t)tile * kOutF4;
        gload_lds16(&g[lane], &sw[lane]);
        gload_lds16(&g[64 + lane], &sw[64 + lane]);
        if (lane < kOutF4 - 128) gload_lds16(&g[128 + lane], &sw[128 + lane]);
        const float4* h = (const float4*)tgt + (size_t)tile * kTgtF4;
        gload_lds16(&h[lane], &sw[kOutF4 + lane]);
        if (lane < kTgtF4 - 64) gload_lds16(&h[64 + lane], &sw[kOutF4 + 64 + lane]);
    }
    // wave-level drain of this wave's LDS-DMA before ds_read (no block barrier).
    // Other resident waves (24-32/CU) keep the memory pipe fed during compute.
    __builtin_amdgcn_s_waitcnt(0);

    // ---- compute: 4 lanes per cell; lane parity p handles anchors {p, p+4, p+8} ----
    const int c = lane >> 2;                 // cell within tile, 0..15
    const int p = lane & 3;                  // anchor phase
    const int cell = tile * kCellsPerTile + c;
    const int gy = cell & (kGY - 1);
    const int gx = (cell >> 7) & (kGX - 1);

    const float* st = swf + 4 * kOutF4 + c * 18;
    const float acx = st[0], acy = st[1], aw = st[2], ah = st[3], conf = st[5];
    const bool pos = conf > 0.8f;

    const float zx = (float)gx * (1.f / kGX) + 0.5f / kGX;
    const float zy = (float)gy * (1.f / kGY) + 0.5f / kGY;
    const float ax1 = acx - 0.5f * aw, ax2 = acx + 0.5f * aw;
    const float ay1 = acy - 0.5f * ah, ay2 = acy + 0.5f * ah;
    const float area_a = aw * ah;
    const float atan_a = fast_atan(aw * frcp(ah));

    const float* ob = swf + c * 45 + p * 5;

    float t_all = 0.f, t_jbb = 0.f, t_huh = 0.f, t_zsd = 0.f;
    float t_jsq = pos ? (p == 0 ? 3.f : 2.f) : 0.f;   // anchors per lane sum to 9

    #pragma unroll
    for (int k = 0; k < 3; ++k) {
        const int a = p + 4 * k;                 // 0..11; a>=9 masked
        const bool act = (a < kA);
        const int off = act ? k * 20 : 0;        // clamp masked read into own cell
        const float o0 = ob[off + 0], o1 = ob[off + 1], o2 = ob[off + 2];
        const float o3 = ob[off + 3], obj = ob[off + 4];

        const float bcx = o0 - 0.5f + zx;
        const float bcy = o1 - 0.5f + zy;
        const float bw  = o2 - 0.5f + (1.f / kGX);
        const float bh  = o3 - 0.5f + (1.f / kGY);
        const float bx1 = bcx - 0.5f * bw, bx2 = bcx + 0.5f * bw;
        const float by1 = bcy - 0.5f * bh, by2 = bcy + 0.5f * bh;

        const float iw = fminf(ax2, bx2) - fmaxf(ax1, bx1);
        const float ih = fminf(ay2, by2) - fmaxf(ay1, by1);
        const float cross = (iw > 0.f && ih > 0.f) ? iw * ih : 0.f;
        const float uni = area_a + bw * bh - cross;
        const float iou = cross * frcp(uni + 1e-6f);

        const float dx = bcx - acx, dy = bcy - acy;
        const float d2 = dx * dx + dy * dy;
        const float cw  = fmaxf(ax2, bx2) - fminf(ax1, bx1);
        const float chh = fmaxf(ay2, by2) - fminf(ay1, by1);
        const float c2 = cw * cw + chh * chh;
        const float diou = iou - d2 * frcp(c2);

        const float dat = atan_a - fast_atan(bw * frcp(bh));
        const float v = 0.4052847345693511f * dat * dat;   // 4/pi^2
        const float alpha = v * frcp(1.f - iou + v);
        const float los = 1.f - (diou - alpha * v);
        const float om = 1.f - obj;

        const bool pp = pos && act;
        t_all += pp ? (los + om) : 0.f;
        t_jbb += pp ? iou : 0.f;
        t_huh += pp ? om : 0.f;
        t_zsd += pp ? om * om : (act ? obj * obj : 0.f);
    }

    // ---- wave-64 butterfly reduce (float: wave partials are small), LDS cross-wave ----
    float vals[5] = {t_jsq, t_all, t_jbb, t_huh, t_zsd};
    #pragma unroll
    for (int i = 0; i < 5; ++i) {
        float x = vals[i];
        #pragma unroll
        for (int off = 32; off > 0; off >>= 1) x += __shfl_down(x, off, 64);
        vals[i] = x;
    }
    if (lane == 0) {
        #pragma unroll
        for (int i = 0; i < 5; ++i) smem[wv][i] = vals[i];
    }
    __syncthreads();
    if (threadIdx.x < 5) {
        const double sv = (double)smem[0][threadIdx.x] + (double)smem[1][threadIdx.x] +
                          (double)smem[2][threadIdx.x] + (double)smem[3][threadIdx.x];
        if (mode) acc[(size_t)blockIdx.x * 5 + threadIdx.x] = sv;
        else atomicAdd(&acc[threadIdx.x], sv);
    }
}

__global__ __launch_bounds__(256)
void loss_final(const double* __restrict__ acc, float* __restrict__ res, int n_part) {
    if (n_part > 0) {
        double v[5] = {0, 0, 0, 0, 0};
        for (int j = threadIdx.x; j < n_part; j += 256) {
            #pragma unroll
            for (int i = 0; i < 5; ++i) v[i] += acc[(size_t)j * 5 + i];
        }
        #pragma unroll
        for (int i = 0; i < 5; ++i) {
            double x = v[i];
            #pragma unroll
            for (int off = 32; off > 0; off >>= 1) x += __shfl_down(x, off, 64);
            v[i] = x;
        }
        __shared__ double sm[4][5];
        const int lane = threadIdx.x & 63, wv = threadIdx.x >> 6;
        if (lane == 0) {
            #pragma unroll
            for (int i = 0; i < 5; ++i) sm[wv][i] = v[i];
        }
        __syncthreads();
        if (threadIdx.x == 0) {
            #pragma unroll
            for (int i = 0; i < 5; ++i) v[i] = sm[0][i] + sm[1][i] + sm[2][i] + sm[3][i];
            const double jsq = v[0], total = (double)kN;
            res[0] = (float)(v[1] / jsq + v[4] / total);
            res[1] = (float)(v[2] / jsq);
            res[2] = (float)(v[3] / jsq);
        }
    } else if (threadIdx.x == 0) {
        const double jsq = acc[0], total = (double)kN;
        res[0] = (float)(acc[1] / jsq + acc[4] / total);
        res[1] = (float)(acc[2] / jsq);
        res[2] = (float)(acc[3] / jsq);
    }
}

extern "C" void kernel_launch(void* const* d_in, const int* in_sizes, int n_in,
                              void* d_out, int out_size, void* d_ws, size_t ws_size,
                              hipStream_t stream) {
    const float* outp = (const float*)d_in[0];
    const float* tgt  = (const float*)d_in[1];
    float* res = (float*)d_out;
    double* acc = (double*)d_ws;

    const bool partials = ws_size >= (size_t)kBlocks * 5 * sizeof(double);  // 320 KB
    if (!partials) hipMemsetAsync(acc, 0, 5 * sizeof(double), stream);
    loss_main<<<kBlocks, 256, 0, stream>>>(outp, tgt, acc, partials ? 1 : 0);
    loss_final<<<1, 256, 0, stream>>>(acc, res, partials ? kBlocks : 0);
}

// Round 7
// 173.999 us; speedup vs baseline: 1.1664x; 1.0108x over previous
//
#include <hip/hip_runtime.h>
#include <math.h>

// Problem shape (fixed): out (32,128,128,9,5) f32, target (32,128,128,3,6) f32
constexpr int kGX     = 128;
constexpr int kGY     = 128;
constexpr int kA      = 9;
constexpr int kNCells = 32 * kGX * kGY;              // 524288
constexpr int kN      = kNCells * kA;                // 4718592

constexpr int kCellsPerTile = 16;
constexpr int kTiles  = kNCells / kCellsPerTile;     // 32768
constexpr int kT      = 8;                           // tiles per wave, pipelined
constexpr int kWaves  = kTiles / kT;                 // 4096
constexpr int kBlocks = kWaves / 4;                  // 1024 (exactly 4 per CU)
static_assert(kBlocks * 4 * kT == kTiles, "exact cover");

constexpr int kOutF4  = kCellsPerTile * 45 / 4;      // 180 float4
constexpr int kTgtF4  = kCellsPerTile * 18 / 4;      // 72 float4
constexpr int kTileF4 = kOutF4 + kTgtF4;             // 252 (4032 B per buffer)

// s_waitcnt simm16 (gfx9): vmcnt[3:0]|expcnt[6:4]|lgkmcnt[11:8]|vmcnt[5:4]@[15:14]
#define WAITCNT_VM5  0x0F75   // vmcnt<=5, expcnt/lgkmcnt unconstrained
#define WAITCNT_VM0  0x0F70   // vmcnt==0, expcnt/lgkmcnt unconstrained

__device__ inline void gload_lds16(const void* gptr, void* lptr) {
    __builtin_amdgcn_global_load_lds(
        (const __attribute__((address_space(1))) unsigned int*)gptr,
        (__attribute__((address_space(3))) unsigned int*)lptr, 16, 0, 0);
}

__device__ inline float frcp(float x) { return __builtin_amdgcn_rcpf(x); }

// Branchless full-range atan, A&S 4.4.49 poly on [0,1] (|eps| <= 1e-5).
__device__ inline float fast_atan(float r) {
    const float x = fabsf(r);
    const bool inv = x > 1.f;
    const float t = inv ? frcp(x) : x;
    const float t2 = t * t;
    float p = fmaf(t2, 0.0208351f, -0.0851330f);
    p = fmaf(t2, p, 0.1801410f);
    p = fmaf(t2, p, -0.3302995f);
    p = fmaf(t2, p, 0.9998660f);
    p = t * p;
    float res = inv ? (1.5707963f - p) : p;
    return r < 0.f ? -res : res;
}

// acc: mode==1 -> per-block partials acc[b*5+i]; mode==0 -> 5 global doubles (atomics)
__global__ __launch_bounds__(256)
void loss_main(const float* __restrict__ outp, const float* __restrict__ tgt,
               double* __restrict__ acc, int mode) {
    __shared__ float4 s_tile[4 * 2 * kTileF4];   // 32256 B: 2 buffers per wave
    __shared__ float smem[4][5];

    const int lane = threadIdx.x & 63;
    const int wv   = threadIdx.x >> 6;
    float4* sb = s_tile + wv * (2 * kTileF4);
    const int tile0 = (blockIdx.x * 4 + wv) * kT;    // 8 consecutive tiles per wave

    const int c = lane >> 2;                 // cell within tile, 0..15
    const int p = lane & 3;                  // anchor phase: anchors {p, p+4, p+8}

    // stage tile (5 DMA instrs, no VGPR staging -> no spill risk)
    auto stage = [&](int t, int buf) {
        const float4* g = (const float4*)outp + (size_t)(tile0 + t) * kOutF4;
        float4* d = sb + buf * kTileF4;
        gload_lds16(&g[lane], &d[lane]);
        gload_lds16(&g[64 + lane], &d[64 + lane]);
        if (lane < kOutF4 - 128) gload_lds16(&g[128 + lane], &d[128 + lane]);
        const float4* h = (const float4*)tgt + (size_t)(tile0 + t) * kTgtF4;
        gload_lds16(&h[lane], &d[kOutF4 + lane]);
        if (lane < kTgtF4 - 64) gload_lds16(&h[64 + lane], &d[kOutF4 + 64 + lane]);
    };

    float t_jsq = 0.f, t_all = 0.f, t_jbb = 0.f, t_huh = 0.f, t_zsd = 0.f;

    stage(0, 0);                             // prologue

    for (int t = 0; t < kT; ++t) {
        if (t + 1 < kT) {
            stage(t + 1, (t + 1) & 1);       // prefetch next tile into other buffer
            // wait ONLY for tile t's 5 DMAs; the 5 prefetch DMAs stay in flight
            // through the entire compute phase below (AITER-style, never vmcnt(0))
            __builtin_amdgcn_s_waitcnt(WAITCNT_VM5);
        } else {
            __builtin_amdgcn_s_waitcnt(WAITCNT_VM0);
        }

        const float* swf = (const float*)(sb + (t & 1) * kTileF4);
        const int tile = tile0 + t;
        const int cell = tile * kCellsPerTile + c;
        const int gy = cell & (kGY - 1);
        const int gx = (cell >> 7) & (kGX - 1);

        const float* st = swf + 4 * kOutF4 + c * 18;
        const float acx = st[0], acy = st[1], aw = st[2], ah = st[3], conf = st[5];
        const bool pos = conf > 0.8f;

        const float zx = (float)gx * (1.f / kGX) + 0.5f / kGX;
        const float zy = (float)gy * (1.f / kGY) + 0.5f / kGY;
        const float ax1 = acx - 0.5f * aw, ax2 = acx + 0.5f * aw;
        const float ay1 = acy - 0.5f * ah, ay2 = acy + 0.5f * ah;
        const float area_a = aw * ah;
        const float atan_a = fast_atan(aw * frcp(ah));

        const float* ob = swf + c * 45 + p * 5;

        t_jsq += pos ? (p == 0 ? 3.f : 2.f) : 0.f;   // anchors/lane sum to 9 per cell

        #pragma unroll
        for (int k = 0; k < 3; ++k) {
            const int a = p + 4 * k;                 // 0..11; a>=9 masked
            const bool act = (a < kA);
            const int off = act ? k * 20 : 0;        // clamp masked read into own cell
            const float o0 = ob[off + 0], o1 = ob[off + 1], o2 = ob[off + 2];
            const float o3 = ob[off + 3], obj = ob[off + 4];

            const float bcx = o0 - 0.5f + zx;
            const float bcy = o1 - 0.5f + zy;
            const float bw  = o2 - 0.5f + (1.f / kGX);
            const float bh  = o3 - 0.5f + (1.f / kGY);
            const float bx1 = bcx - 0.5f * bw, bx2 = bcx + 0.5f * bw;
            const float by1 = bcy - 0.5f * bh, by2 = bcy + 0.5f * bh;

            const float iw = fminf(ax2, bx2) - fmaxf(ax1, bx1);
            const float ih = fminf(ay2, by2) - fmaxf(ay1, by1);
            const float cross = (iw > 0.f && ih > 0.f) ? iw * ih : 0.f;
            const float uni = area_a + bw * bh - cross;
            const float iou = cross * frcp(uni + 1e-6f);

            const float dx = bcx - acx, dy = bcy - acy;
            const float d2 = dx * dx + dy * dy;
            const float cw  = fmaxf(ax2, bx2) - fminf(ax1, bx1);
            const float chh = fmaxf(ay2, by2) - fminf(ay1, by1);
            const float c2 = cw * cw + chh * chh;
            const float diou = iou - d2 * frcp(c2);

            const float dat = atan_a - fast_atan(bw * frcp(bh));
            const float v = 0.4052847345693511f * dat * dat;   // 4/pi^2
            const float alpha = v * frcp(1.f - iou + v);
            const float los = 1.f - (diou - alpha * v);
            const float om = 1.f - obj;

            const bool pp = pos && act;
            t_all += pp ? (los + om) : 0.f;
            t_jbb += pp ? iou : 0.f;
            t_huh += pp ? om : 0.f;
            t_zsd += pp ? om * om : (act ? obj * obj : 0.f);
        }
    }

    // ---- wave-64 butterfly reduce (float: wave partials are small), LDS cross-wave ----
    float vals[5] = {t_jsq, t_all, t_jbb, t_huh, t_zsd};
    #pragma unroll
    for (int i = 0; i < 5; ++i) {
        float x = vals[i];
        #pragma unroll
        for (int off = 32; off > 0; off >>= 1) x += __shfl_down(x, off, 64);
        vals[i] = x;
    }
    if (lane == 0) {
        #pragma unroll
        for (int i = 0; i < 5; ++i) smem[wv][i] = vals[i];
    }
    __syncthreads();
    if (threadIdx.x < 5) {
        const double sv = (double)smem[0][threadIdx.x] + (double)smem[1][threadIdx.x] +
                          (double)smem[2][threadIdx.x] + (double)smem[3][threadIdx.x];
        if (mode) acc[(size_t)blockIdx.x * 5 + threadIdx.x] = sv;
        else atomicAdd(&acc[threadIdx.x], sv);
    }
}

__global__ __launch_bounds__(256)
void loss_final(const double* __restrict__ acc, float* __restrict__ res, int n_part) {
    if (n_part > 0) {
        double v[5] = {0, 0, 0, 0, 0};
        for (int j = threadIdx.x; j < n_part; j += 256) {
            #pragma unroll
            for (int i = 0; i < 5; ++i) v[i] += acc[(size_t)j * 5 + i];
        }
        #pragma unroll
        for (int i = 0; i < 5; ++i) {
            double x = v[i];
            #pragma unroll
            for (int off = 32; off > 0; off >>= 1) x += __shfl_down(x, off, 64);
            v[i] = x;
        }
        __shared__ double sm[4][5];
        const int lane = threadIdx.x & 63, wv = threadIdx.x >> 6;
        if (lane == 0) {
            #pragma unroll
            for (int i = 0; i < 5; ++i) sm[wv][i] = v[i];
        }
        __syncthreads();
        if (threadIdx.x == 0) {
            #pragma unroll
            for (int i = 0; i < 5; ++i) v[i] = sm[0][i] + sm[1][i] + sm[2][i] + sm[3][i];
            const double jsq = v[0], total = (double)kN;
            res[0] = (float)(v[1] / jsq + v[4] / total);
            res[1] = (float)(v[2] / jsq);
            res[2] = (float)(v[3] / jsq);
        }
    } else if (threadIdx.x == 0) {
        const double jsq = acc[0], total = (double)kN;
        res[0] = (float)(acc[1] / jsq + acc[4] / total);
        res[1] = (float)(acc[2] / jsq);
        res[2] = (float)(acc[3] / jsq);
    }
}

extern "C" void kernel_launch(void* const* d_in, const int* in_sizes, int n_in,
                              void* d_out, int out_size, void* d_ws, size_t ws_size,
                              hipStream_t stream) {
    const float* outp = (const float*)d_in[0];
    const float* tgt  = (const float*)d_in[1];
    float* res = (float*)d_out;
    double* acc = (double*)d_ws;

    const bool partials = ws_size >= (size_t)kBlocks * 5 * sizeof(double);  // 40 KB
    if (!partials) hipMemsetAsync(acc, 0, 5 * sizeof(double), stream);
    loss_main<<<kBlocks, 256, 0, stream>>>(outp, tgt, acc, partials ? 1 : 0);
    loss_final<<<1, 256, 0, stream>>>(acc, res, partials ? kBlocks : 0);
}

// Round 8
// 170.375 us; speedup vs baseline: 1.1912x; 1.0213x over previous
//
#include <hip/hip_runtime.h>
#include <math.h>

// Problem shape (fixed): out (32,128,128,9,5) f32, target (32,128,128,3,6) f32
constexpr int kGX     = 128;
constexpr int kGY     = 128;
constexpr int kA      = 9;
constexpr int kNCells = 32 * kGX * kGY;              // 524288
constexpr int kN      = kNCells * kA;                // 4718592

constexpr int kGroups = kN / 4;                      // 1179648 (4 anchors/thread)
constexpr int kBlocks = kGroups / 256;               // 4608
static_assert(kBlocks * 256 * 4 == kN, "exact cover");

__device__ inline float frcp(float x) { return __builtin_amdgcn_rcpf(x); }

// Branchless full-range atan, A&S 4.4.49 poly on [0,1] (|eps| <= 1e-5).
__device__ inline float fast_atan(float r) {
    const float x = fabsf(r);
    const bool inv = x > 1.f;
    const float t = inv ? frcp(x) : x;
    const float t2 = t * t;
    float p = fmaf(t2, 0.0208351f, -0.0851330f);
    p = fmaf(t2, p, 0.1801410f);
    p = fmaf(t2, p, -0.3302995f);
    p = fmaf(t2, p, 0.9998660f);
    p = t * p;
    float res = inv ? (1.5707963f - p) : p;
    return r < 0.f ? -res : res;
}

struct Rec {   // per-cell precomputed invariants
    float ax1, ax2, ay1, ay2, acx, acy, area, atg, zx, zy, posf;
};

__device__ inline Rec make_rec(const float* __restrict__ tgt, int cell) {
    const float2* t2p = (const float2*)(tgt + (size_t)cell * 18);
    const float2 a01 = t2p[0];               // acx, acy
    const float2 a23 = t2p[1];               // aw, ah
    const float conf = ((const float*)t2p)[5];
    Rec r;
    r.acx = a01.x; r.acy = a01.y;
    r.ax1 = a01.x - 0.5f * a23.x; r.ax2 = a01.x + 0.5f * a23.x;
    r.ay1 = a01.y - 0.5f * a23.y; r.ay2 = a01.y + 0.5f * a23.y;
    r.area = a23.x * a23.y;
    r.atg  = fast_atan(a23.x * frcp(a23.y));
    const int gy = cell & (kGY - 1);
    const int gx = (cell >> 7) & (kGX - 1);
    r.zx = (float)gx * (1.f / kGX) + 0.5f / kGX;
    r.zy = (float)gy * (1.f / kGY) + 0.5f / kGY;
    r.posf = (conf > 0.8f) ? 1.f : 0.f;
    return r;
}

// acc: mode==1 -> per-block partials acc[b*5+i]; mode==0 -> 5 global doubles (atomics)
__global__ __launch_bounds__(256)
void loss_main(const float* __restrict__ outp, const float* __restrict__ tgt,
               double* __restrict__ acc, int mode) {
    const int gid = blockIdx.x * 256 + threadIdx.x;  // group id, 4 anchors
    const int a0  = gid * 4;

    // ---- loads straight to registers: compiler tracks vmcnt per register ----
    const float4* o4 = (const float4*)outp + (size_t)gid * 5;
    const float4 q0 = o4[0], q1 = o4[1], q2 = o4[2], q3 = o4[3], q4 = o4[4];

    const int cell0 = (int)(__umulhi((unsigned)a0, 0x38E38E39u) >> 1);  // a0/9
    const int r0    = a0 - cell0 * 9;
    const int cell1 = min(cell0 + 1, kNCells - 1);   // clamp (never selected if OOB)

    const Rec RA = make_rec(tgt, cell0);
    const Rec RB = make_rec(tgt, cell1);

    // flatten the 5 float4 into per-anchor scalars (compile-time indexed)
    const float o[20] = {q0.x, q0.y, q0.z, q0.w, q1.x, q1.y, q1.z, q1.w,
                         q2.x, q2.y, q2.z, q2.w, q3.x, q3.y, q3.z, q3.w,
                         q4.x, q4.y, q4.z, q4.w};

    float t_jsq = 0.f, t_all = 0.f, t_jbb = 0.f, t_huh = 0.f, t_zsd = 0.f;

    #pragma unroll
    for (int j = 0; j < 4; ++j) {
        const bool cross = (r0 + j) >= 9;
        // select cell record (v_cndmask chain; no memory)
        const float ax1 = cross ? RB.ax1 : RA.ax1, ax2 = cross ? RB.ax2 : RA.ax2;
        const float ay1 = cross ? RB.ay1 : RA.ay1, ay2 = cross ? RB.ay2 : RA.ay2;
        const float acx = cross ? RB.acx : RA.acx, acy = cross ? RB.acy : RA.acy;
        const float area_a = cross ? RB.area : RA.area;
        const float atan_a = cross ? RB.atg : RA.atg;
        const float zx = cross ? RB.zx : RA.zx, zy = cross ? RB.zy : RA.zy;
        const float posf = cross ? RB.posf : RA.posf;
        const bool pos = posf > 0.5f;

        const float o0 = o[j * 5 + 0], o1 = o[j * 5 + 1], o2 = o[j * 5 + 2];
        const float o3 = o[j * 5 + 3], obj = o[j * 5 + 4];

        const float bcx = o0 - 0.5f + zx;
        const float bcy = o1 - 0.5f + zy;
        const float bw  = o2 - 0.5f + (1.f / kGX);
        const float bh  = o3 - 0.5f + (1.f / kGY);
        const float bx1 = bcx - 0.5f * bw, bx2 = bcx + 0.5f * bw;
        const float by1 = bcy - 0.5f * bh, by2 = bcy + 0.5f * bh;

        const float iw = fminf(ax2, bx2) - fmaxf(ax1, bx1);
        const float ih = fminf(ay2, by2) - fmaxf(ay1, by1);
        const float cross_a = (iw > 0.f && ih > 0.f) ? iw * ih : 0.f;
        const float uni = area_a + bw * bh - cross_a;
        const float iou = cross_a * frcp(uni + 1e-6f);

        const float dx = bcx - acx, dy = bcy - acy;
        const float d2 = dx * dx + dy * dy;
        const float cw  = fmaxf(ax2, bx2) - fminf(ax1, bx1);
        const float chh = fmaxf(ay2, by2) - fminf(ay1, by1);
        const float c2 = cw * cw + chh * chh;
        const float diou = iou - d2 * frcp(c2);

        const float dat = atan_a - fast_atan(bw * frcp(bh));
        const float v = 0.4052847345693511f * dat * dat;   // 4/pi^2
        const float alpha = v * frcp(1.f - iou + v);
        const float los = 1.f - (diou - alpha * v);
        const float om = 1.f - obj;

        t_jsq += posf;
        t_all += pos ? (los + om) : 0.f;
        t_jbb += pos ? iou : 0.f;
        t_huh += pos ? om : 0.f;
        t_zsd += pos ? om * om : obj * obj;
    }

    // ---- wave-64 butterfly reduce (float), cross-wave via LDS, block partial ----
    const int lane = threadIdx.x & 63;
    const int wv   = threadIdx.x >> 6;
    float vals[5] = {t_jsq, t_all, t_jbb, t_huh, t_zsd};
    #pragma unroll
    for (int i = 0; i < 5; ++i) {
        float x = vals[i];
        #pragma unroll
        for (int off = 32; off > 0; off >>= 1) x += __shfl_down(x, off, 64);
        vals[i] = x;
    }
    __shared__ float smem[4][5];
    if (lane == 0) {
        #pragma unroll
        for (int i = 0; i < 5; ++i) smem[wv][i] = vals[i];
    }
    __syncthreads();
    if (threadIdx.x < 5) {
        const double sv = (double)smem[0][threadIdx.x] + (double)smem[1][threadIdx.x] +
                          (double)smem[2][threadIdx.x] + (double)smem[3][threadIdx.x];
        if (mode) acc[(size_t)blockIdx.x * 5 + threadIdx.x] = sv;
        else atomicAdd(&acc[threadIdx.x], sv);
    }
}

__global__ __launch_bounds__(256)
void loss_final(const double* __restrict__ acc, float* __restrict__ res, int n_part) {
    if (n_part > 0) {
        double v[5] = {0, 0, 0, 0, 0};
        for (int j = threadIdx.x; j < n_part; j += 256) {
            #pragma unroll
            for (int i = 0; i < 5; ++i) v[i] += acc[(size_t)j * 5 + i];
        }
        #pragma unroll
        for (int i = 0; i < 5; ++i) {
            double x = v[i];
            #pragma unroll
            for (int off = 32; off > 0; off >>= 1) x += __shfl_down(x, off, 64);
            v[i] = x;
        }
        __shared__ double sm[4][5];
        const int lane = threadIdx.x & 63, wv = threadIdx.x >> 6;
        if (lane == 0) {
            #pragma unroll
            for (int i = 0; i < 5; ++i) sm[wv][i] = v[i];
        }
        __syncthreads();
        if (threadIdx.x == 0) {
            #pragma unroll
            for (int i = 0; i < 5; ++i) v[i] = sm[0][i] + sm[1][i] + sm[2][i] + sm[3][i];
            const double jsq = v[0], total = (double)kN;
            res[0] = (float)(v[1] / jsq + v[4] / total);
            res[1] = (float)(v[2] / jsq);
            res[2] = (float)(v[3] / jsq);
        }
    } else if (threadIdx.x == 0) {
        const double jsq = acc[0], total = (double)kN;
        res[0] = (float)(acc[1] / jsq + acc[4] / total);
        res[1] = (float)(acc[2] / jsq);
        res[2] = (float)(acc[3] / jsq);
    }
}

extern "C" void kernel_launch(void* const* d_in, const int* in_sizes, int n_in,
                              void* d_out, int out_size, void* d_ws, size_t ws_size,
                              hipStream_t stream) {
    const float* outp = (const float*)d_in[0];
    const float* tgt  = (const float*)d_in[1];
    float* res = (float*)d_out;
    double* acc = (double*)d_ws;

    const bool partials = ws_size >= (size_t)kBlocks * 5 * sizeof(double);  // 184 KB
    if (!partials) hipMemsetAsync(acc, 0, 5 * sizeof(double), stream);
    loss_main<<<kBlocks, 256, 0, stream>>>(outp, tgt, acc, partials ? 1 : 0);
    loss_final<<<1, 256, 0, stream>>>(acc, res, partials ? kBlocks : 0);
}